// Round 1
// baseline (669.032 us; speedup 1.0000x reference)
//
#include <hip/hip_runtime.h>

// SumPooling / segment_sum: out[s, d] = sum_{i: index[i]==s} x[i, d]
// x: (1e6, 128) fp32, index: (1e6,) sorted int, out: (16384, 128) fp32.
//
// v2 strategy: one 64-lane wave per 128-row chunk.
//  - lanes 0-31 process even rows, lanes 32-63 odd rows: float4/lane
//    => 1 KiB per global_load instruction (coalescing sweet spot).
//  - the wave's 128 indices are pre-staged into registers (one int2/lane)
//    and broadcast per row via __shfl => no index load on the critical path.
//  - loads batched 4 pairs (8 rows) deep => 4 loads in flight per wave,
//    breaking the load->branch serialization of v1.
//  - run-length accumulate per half-wave (index sorted); atomicAdd only at
//    segment boundaries / chunk edges.

constexpr int D_FEAT = 128;
constexpr int D4 = D_FEAT / 4;            // float4 elements per row = 32
constexpr int ROWS_PER_WAVE = 128;
constexpr int WAVES_PER_BLOCK = 4;        // block = 256 threads

__global__ void zero_out_kernel(float4* __restrict__ out, int n4) {
    int i = blockIdx.x * blockDim.x + threadIdx.x;
    int stride = gridDim.x * blockDim.x;
    for (; i < n4; i += stride) {
        out[i] = make_float4(0.f, 0.f, 0.f, 0.f);
    }
}

__device__ __forceinline__ void flush_acc(float* __restrict__ out, int seg,
                                          int cq, const float4& a) {
    float* o = out + (long)seg * D_FEAT + cq * 4;
    atomicAdd(o + 0, a.x);
    atomicAdd(o + 1, a.y);
    atomicAdd(o + 2, a.z);
    atomicAdd(o + 3, a.w);
}

__global__ __launch_bounds__(256) void segsum_kernel(
        const float* __restrict__ x,
        const int* __restrict__ index,
        float* __restrict__ out,
        int n_rows) {
    const int lane = threadIdx.x & 63;
    const int half = lane >> 5;            // 0: even rows, 1: odd rows
    const int cq   = lane & 31;            // float4 column within the row
    const long wave = (long)blockIdx.x * WAVES_PER_BLOCK + (threadIdx.x >> 6);

    long row0 = wave * ROWS_PER_WAVE;
    if (row0 >= n_rows) return;
    long rend = row0 + ROWS_PER_WAVE;
    if (rend > n_rows) rend = n_rows;
    const int nr = (int)(rend - row0);
    const int npairs = nr >> 1;
    const int odd = nr & 1;

    // Stage this wave's 128 indices: lane l holds rows row0+2l, row0+2l+1.
    int2 myidx = make_int2(0, 0);
    {
        long ib = row0 + 2 * lane;
        if (ib + 1 < (long)n_rows) {
            myidx = *(const int2*)(index + ib);
        } else if (ib < (long)n_rows) {
            myidx.x = index[ib];
        }
    }

    const float4* __restrict__ x4 = (const float4*)x;

    // Per-half-wave running state. For nr==1, half 1 never accumulates and
    // flushes 0.0 into segment 0 (harmless).
    int sx0 = __shfl(myidx.x, 0);
    int sy0 = __shfl(myidx.y, 0);
    int cur_seg = half ? sy0 : sx0;
    float4 acc = make_float4(0.f, 0.f, 0.f, 0.f);

    // Address of this lane's float4 in row (row0 + 2p + half):
    const long base = (row0 + half) * D4 + cq;

    int p = 0;
    constexpr int U = 4;  // pairs per batch => 8 rows, 4 loads in flight
    for (; p + U <= npairs; p += U) {
        // Issue all loads first (no branches between them).
        float4 v0 = x4[base + (long)(2 * (p + 0)) * D4];
        float4 v1 = x4[base + (long)(2 * (p + 1)) * D4];
        float4 v2 = x4[base + (long)(2 * (p + 2)) * D4];
        float4 v3 = x4[base + (long)(2 * (p + 3)) * D4];

        {
            int sx = __shfl(myidx.x, p + 0), sy = __shfl(myidx.y, p + 0);
            int s = half ? sy : sx;
            if (s != cur_seg) { flush_acc(out, cur_seg, cq, acc); cur_seg = s; acc = v0; }
            else { acc.x += v0.x; acc.y += v0.y; acc.z += v0.z; acc.w += v0.w; }
        }
        {
            int sx = __shfl(myidx.x, p + 1), sy = __shfl(myidx.y, p + 1);
            int s = half ? sy : sx;
            if (s != cur_seg) { flush_acc(out, cur_seg, cq, acc); cur_seg = s; acc = v1; }
            else { acc.x += v1.x; acc.y += v1.y; acc.z += v1.z; acc.w += v1.w; }
        }
        {
            int sx = __shfl(myidx.x, p + 2), sy = __shfl(myidx.y, p + 2);
            int s = half ? sy : sx;
            if (s != cur_seg) { flush_acc(out, cur_seg, cq, acc); cur_seg = s; acc = v2; }
            else { acc.x += v2.x; acc.y += v2.y; acc.z += v2.z; acc.w += v2.w; }
        }
        {
            int sx = __shfl(myidx.x, p + 3), sy = __shfl(myidx.y, p + 3);
            int s = half ? sy : sx;
            if (s != cur_seg) { flush_acc(out, cur_seg, cq, acc); cur_seg = s; acc = v3; }
            else { acc.x += v3.x; acc.y += v3.y; acc.z += v3.z; acc.w += v3.w; }
        }
    }
    // Remainder pairs.
    for (; p < npairs; ++p) {
        float4 v = x4[base + (long)(2 * p) * D4];
        int sx = __shfl(myidx.x, p), sy = __shfl(myidx.y, p);
        int s = half ? sy : sx;
        if (s != cur_seg) { flush_acc(out, cur_seg, cq, acc); cur_seg = s; acc = v; }
        else { acc.x += v.x; acc.y += v.y; acc.z += v.z; acc.w += v.w; }
    }
    // Odd last row: processed by half 0 only. (Shuffle outside the branch.)
    if (odd) {
        int s = __shfl(myidx.x, npairs);
        if (half == 0) {
            float4 v = x4[(rend - 1) * D4 + cq];
            if (s != cur_seg) { flush_acc(out, cur_seg, cq, acc); cur_seg = s; acc = v; }
            else { acc.x += v.x; acc.y += v.y; acc.z += v.z; acc.w += v.w; }
        }
    }

    flush_acc(out, cur_seg, cq, acc);
}

extern "C" void kernel_launch(void* const* d_in, const int* in_sizes, int n_in,
                              void* d_out, int out_size, void* d_ws, size_t ws_size,
                              hipStream_t stream) {
    const float* x = (const float*)d_in[0];
    const int* index = (const int*)d_in[1];
    float* out = (float*)d_out;

    const int n_rows = in_sizes[1];           // 1,000,000
    const int n_out4 = out_size / 4;          // out_size = 16384*128

    // Zero the (poisoned) output first.
    zero_out_kernel<<<256, 256, 0, stream>>>((float4*)out, n_out4);

    const long n_waves = ((long)n_rows + ROWS_PER_WAVE - 1) / ROWS_PER_WAVE;
    const int n_blocks = (int)((n_waves + WAVES_PER_BLOCK - 1) / WAVES_PER_BLOCK);
    segsum_kernel<<<n_blocks, 256, 0, stream>>>(x, index, out, n_rows);
}